// Round 5
// baseline (810.549 us; speedup 1.0000x reference)
//
#include <hip/hip_runtime.h>
#include <hip/hip_fp16.h>

#define NSEQ 8192
#define DIM  512
#define SPITCH 8256            // f32 elems per S row (NSEQ + 64, kills pow2 stride)
#define SROWB  33024           // bytes per S row
#define VPITCH 8256            // f16 elems per XhT row

typedef _Float16 f16;
typedef _Float16 f16x8 __attribute__((ext_vector_type(8)));
typedef _Float16 f16x4 __attribute__((ext_vector_type(4)));
typedef float    f32x4 __attribute__((ext_vector_type(4)));

// ---------------------------------------------------------------------------
// X (fp32) -> Xh + Xl (f16 hi/lo split), elementwise.
// ---------------------------------------------------------------------------
__global__ __launch_bounds__(256) void k_splitx(const float* __restrict__ X,
                                                f16* __restrict__ Xh,
                                                f16* __restrict__ Xl)
{
  const size_t idx = (size_t)blockIdx.x * 256 + threadIdx.x;
  f32x4 v = *(const f32x4*)(X + idx * 4);
  f16x4 h, l;
#pragma unroll
  for (int i = 0; i < 4; ++i) {
    h[i] = (f16)v[i];
    l[i] = (f16)(v[i] - (float)h[i]);
  }
  *(f16x4*)(Xh + idx * 4) = h;
  *(f16x4*)(Xl + idx * 4) = l;
}

// ---------------------------------------------------------------------------
// W (512x512 fp32) -> Wt^T split: Wth/Wtl[c][k] = split(W[k][c]).
// ---------------------------------------------------------------------------
__global__ __launch_bounds__(256) void k_splitwt(const float* __restrict__ W,
                                                 f16* __restrict__ Th,
                                                 f16* __restrict__ Tl)
{
  __shared__ float T[64][65];
  const int tid = threadIdx.x;
  const int k0 = blockIdx.x * 64;   // input row
  const int c0 = blockIdx.y * 64;   // input col
#pragma unroll
  for (int e = 0; e < 16; ++e) {
    int idx = tid + e * 256;
    T[idx >> 6][idx & 63] = W[(size_t)(k0 + (idx >> 6)) * DIM + c0 + (idx & 63)];
  }
  __syncthreads();
#pragma unroll
  for (int e = 0; e < 16; ++e) {
    int idx = tid + e * 256;
    int cc = idx >> 6, kk = idx & 63;
    float v = T[kk][cc];
    f16 h = (f16)v;
    Th[(size_t)(c0 + cc) * DIM + k0 + kk] = h;
    Tl[(size_t)(c0 + cc) * DIM + k0 + kk] = (f16)(v - (float)h);
  }
}

// ---------------------------------------------------------------------------
// Kernel 0b: XhT[d][j] = f16(X[j][d])  (V in [d][j] layout, padded pitch)
// ---------------------------------------------------------------------------
__global__ __launch_bounds__(256) void k_xt(const float* __restrict__ X,
                                            f16* __restrict__ XhT)
{
  __shared__ float T[64][65];
  const int tid = threadIdx.x;
  const int j0 = blockIdx.x * 64;
  const int d0 = blockIdx.y * 64;
#pragma unroll
  for (int e = 0; e < 16; ++e) {
    int idx = tid + e * 256;
    T[idx >> 6][idx & 63] = X[(size_t)(j0 + (idx >> 6)) * DIM + d0 + (idx & 63)];
  }
  __syncthreads();
#pragma unroll
  for (int e = 0; e < 16; ++e) {
    int idx = tid + e * 256;
    int dd = idx >> 6, jj = idx & 63;
    XhT[(size_t)(d0 + dd) * VPITCH + j0 + jj] = (f16)T[jj][dd];
  }
}

// ---------------------------------------------------------------------------
// Projection via split-f16 MFMA: C = X W  (M=8192, N=512, K=512).
// Same skeleton as k_qkt: 128x128 tile, 4 waves, BK=32, 3-term split.
// Epilogue: c *= scale, split into Oh (f16 hi) + Ol (f16 lo).
// ---------------------------------------------------------------------------
__global__ __launch_bounds__(256) void k_proj(
    const f16* __restrict__ Xh, const f16* __restrict__ Xl,
    const f16* __restrict__ Wth, const f16* __restrict__ Wtl,
    f16* __restrict__ Oh, f16* __restrict__ Ol, float scale)
{
  __shared__ char sm[4 * 8192];   // Xh,Xl,Wth,Wtl tiles: [128][32] f16
  const int tid  = threadIdx.x;
  const int lane = tid & 63;
  const int w    = tid >> 6;
  const int wm   = (w >> 1) * 64;
  const int wn   = (w & 1) * 64;
  const int row0g = blockIdx.x * 128;   // seq rows
  const int col0g = blockIdx.y * 128;   // out channels (Wt rows)

  const int r1 = tid >> 2;
  const int o1 = (tid & 3) * 8;
  const int sw1 = (r1 * 64 + (tid & 3) * 16) ^ ((r1 & 7) << 4);
  const int sw2 = ((r1 + 64) * 64 + (tid & 3) * 16) ^ (((r1 + 64) & 7) << 4);
  const f16* pAh = Xh  + (size_t)(row0g + r1) * DIM + o1;
  const f16* pAl = Xl  + (size_t)(row0g + r1) * DIM + o1;
  const f16* pBh = Wth + (size_t)(col0g + r1) * DIM + o1;
  const f16* pBl = Wtl + (size_t)(col0g + r1) * DIM + o1;
  const int R64 = 64 * DIM;

  const int frow = lane & 15;
  const int fkb  = (lane >> 4) * 16;

  f32x4 acc[4][4] = {};

  for (int step = 0; step < 16; ++step) {
    const int d0 = step * 32;
    uint4 v0 = *(const uint4*)(pAh + d0);
    uint4 v1 = *(const uint4*)(pAh + R64 + d0);
    uint4 v2 = *(const uint4*)(pAl + d0);
    uint4 v3 = *(const uint4*)(pAl + R64 + d0);
    uint4 v4 = *(const uint4*)(pBh + d0);
    uint4 v5 = *(const uint4*)(pBh + R64 + d0);
    uint4 v6 = *(const uint4*)(pBl + d0);
    uint4 v7 = *(const uint4*)(pBl + R64 + d0);
    __syncthreads();
    *(uint4*)(sm +     0 + sw1) = v0;
    *(uint4*)(sm +     0 + sw2) = v1;
    *(uint4*)(sm +  8192 + sw1) = v2;
    *(uint4*)(sm +  8192 + sw2) = v3;
    *(uint4*)(sm + 16384 + sw1) = v4;
    *(uint4*)(sm + 16384 + sw2) = v5;
    *(uint4*)(sm + 24576 + sw1) = v6;
    *(uint4*)(sm + 24576 + sw2) = v7;
    __syncthreads();
    f16x8 aH[4], aL[4], bH[4], bL[4];
#pragma unroll
    for (int m = 0; m < 4; ++m) {
      int ra = wm + m * 16 + frow;
      int rb = wn + m * 16 + frow;
      int sa = (ra * 64 + fkb) ^ ((ra & 7) << 4);
      int sb = (rb * 64 + fkb) ^ ((rb & 7) << 4);
      aH[m] = *(const f16x8*)(sm +     0 + sa);
      aL[m] = *(const f16x8*)(sm +  8192 + sa);
      bH[m] = *(const f16x8*)(sm + 16384 + sb);
      bL[m] = *(const f16x8*)(sm + 24576 + sb);
    }
#pragma unroll
    for (int m = 0; m < 4; ++m)
#pragma unroll
      for (int n = 0; n < 4; ++n) {
        acc[m][n] = __builtin_amdgcn_mfma_f32_16x16x32_f16(aH[m], bH[n], acc[m][n], 0, 0, 0);
        acc[m][n] = __builtin_amdgcn_mfma_f32_16x16x32_f16(aH[m], bL[n], acc[m][n], 0, 0, 0);
        acc[m][n] = __builtin_amdgcn_mfma_f32_16x16x32_f16(aL[m], bH[n], acc[m][n], 0, 0, 0);
      }
  }

  const int row0 = row0g + wm;
  const int col0 = col0g + wn;
#pragma unroll
  for (int m = 0; m < 4; ++m)
#pragma unroll
    for (int n = 0; n < 4; ++n) {
      int row = row0 + m * 16 + (lane >> 4) * 4;
      int col = col0 + n * 16 + frow;
#pragma unroll
      for (int r = 0; r < 4; ++r) {
        float c = acc[m][n][r] * scale;
        f16 h = (f16)c;
        Oh[(size_t)(row + r) * DIM + col] = h;
        Ol[(size_t)(row + r) * DIM + col] = (f16)(c - (float)h);
      }
    }
}

// ---------------------------------------------------------------------------
// Pass A: S = Q K^T via split-f16 MFMA (3 mfma per fragment pair).
// 128x128 block tile, 4 waves (64x64 each), BK=32, XOR-swizzled LDS.
// ---------------------------------------------------------------------------
__global__ __launch_bounds__(256) void k_qkt(
    const f16* __restrict__ Qh, const f16* __restrict__ Ql,
    const f16* __restrict__ Kh, const f16* __restrict__ Kl,
    float* __restrict__ S, int q0)
{
  __shared__ char sm[4 * 8192];
  const int tid  = threadIdx.x;
  const int lane = tid & 63;
  const int w    = tid >> 6;
  const int wm   = (w >> 1) * 64;
  const int wn   = (w & 1) * 64;
  const int qrow0 = q0 + blockIdx.x * 128;
  const int krow0 = blockIdx.y * 128;

  const int r1 = tid >> 2;
  const int o1 = (tid & 3) * 8;
  const int sw1 = (r1 * 64 + (tid & 3) * 16) ^ ((r1 & 7) << 4);
  const int sw2 = ((r1 + 64) * 64 + (tid & 3) * 16) ^ (((r1 + 64) & 7) << 4);
  const f16* pQh = Qh + (size_t)(qrow0 + r1) * DIM + o1;
  const f16* pQl = Ql + (size_t)(qrow0 + r1) * DIM + o1;
  const f16* pKh = Kh + (size_t)(krow0 + r1) * DIM + o1;
  const f16* pKl = Kl + (size_t)(krow0 + r1) * DIM + o1;
  const int R64 = 64 * DIM;

  const int frow = lane & 15;
  const int fkb  = (lane >> 4) * 16;

  f32x4 acc[4][4] = {};

  for (int step = 0; step < 16; ++step) {
    const int d0 = step * 32;
    uint4 v0 = *(const uint4*)(pQh + d0);
    uint4 v1 = *(const uint4*)(pQh + R64 + d0);
    uint4 v2 = *(const uint4*)(pQl + d0);
    uint4 v3 = *(const uint4*)(pQl + R64 + d0);
    uint4 v4 = *(const uint4*)(pKh + d0);
    uint4 v5 = *(const uint4*)(pKh + R64 + d0);
    uint4 v6 = *(const uint4*)(pKl + d0);
    uint4 v7 = *(const uint4*)(pKl + R64 + d0);
    __syncthreads();
    *(uint4*)(sm +     0 + sw1) = v0;
    *(uint4*)(sm +     0 + sw2) = v1;
    *(uint4*)(sm +  8192 + sw1) = v2;
    *(uint4*)(sm +  8192 + sw2) = v3;
    *(uint4*)(sm + 16384 + sw1) = v4;
    *(uint4*)(sm + 16384 + sw2) = v5;
    *(uint4*)(sm + 24576 + sw1) = v6;
    *(uint4*)(sm + 24576 + sw2) = v7;
    __syncthreads();
    f16x8 aH[4], aL[4], bH[4], bL[4];
#pragma unroll
    for (int m = 0; m < 4; ++m) {
      int ra = wm + m * 16 + frow;
      int rb = wn + m * 16 + frow;
      int sa = (ra * 64 + fkb) ^ ((ra & 7) << 4);
      int sb = (rb * 64 + fkb) ^ ((rb & 7) << 4);
      aH[m] = *(const f16x8*)(sm +     0 + sa);
      aL[m] = *(const f16x8*)(sm +  8192 + sa);
      bH[m] = *(const f16x8*)(sm + 16384 + sb);
      bL[m] = *(const f16x8*)(sm + 24576 + sb);
    }
#pragma unroll
    for (int m = 0; m < 4; ++m)
#pragma unroll
      for (int n = 0; n < 4; ++n) {
        acc[m][n] = __builtin_amdgcn_mfma_f32_16x16x32_f16(aH[m], bH[n], acc[m][n], 0, 0, 0);
        acc[m][n] = __builtin_amdgcn_mfma_f32_16x16x32_f16(aH[m], bL[n], acc[m][n], 0, 0, 0);
        acc[m][n] = __builtin_amdgcn_mfma_f32_16x16x32_f16(aL[m], bH[n], acc[m][n], 0, 0, 0);
      }
  }

  const int srow0 = blockIdx.x * 128 + wm;
  const int scol0 = krow0 + wn;
#pragma unroll
  for (int m = 0; m < 4; ++m)
#pragma unroll
    for (int n = 0; n < 4; ++n) {
      int row = srow0 + m * 16 + (lane >> 4) * 4;
      int col = scol0 + n * 16 + (lane & 15);
#pragma unroll
      for (int r = 0; r < 4; ++r)
        S[(size_t)(row + r) * SPITCH + col] = acc[m][n][r];
    }
}

// ---------------------------------------------------------------------------
// Pass B: one block per row. Row max + sum(exp), writes P=f16(exp(s-m)) and
// the row sum.
// ---------------------------------------------------------------------------
__global__ __launch_bounds__(256) void k_softmax(
    const float* __restrict__ S, f16* __restrict__ P,
    float* __restrict__ Lsum, int q0, int ppitch)
{
  __shared__ float red[4], red2[4];
  const int tid = threadIdx.x;
  const int r = blockIdx.x;
  const float* srow = S + (size_t)r * SPITCH;
  f32x4 v[8];
#pragma unroll
  for (int e = 0; e < 8; ++e)
    v[e] = *(const f32x4*)(srow + (size_t)(tid + e * 256) * 4);
  float m = -3.0e38f;
#pragma unroll
  for (int e = 0; e < 8; ++e)
#pragma unroll
    for (int i = 0; i < 4; ++i) m = fmaxf(m, v[e][i]);
#pragma unroll
  for (int off = 32; off; off >>= 1) m = fmaxf(m, __shfl_xor(m, off));
  if ((tid & 63) == 0) red[tid >> 6] = m;
  __syncthreads();
  m = fmaxf(fmaxf(red[0], red[1]), fmaxf(red[2], red[3]));
  float sum = 0.f;
#pragma unroll
  for (int e = 0; e < 8; ++e)
#pragma unroll
    for (int i = 0; i < 4; ++i) {
      float p = __expf(v[e][i] - m);
      v[e][i] = p;
      sum += p;
    }
#pragma unroll
  for (int off = 32; off; off >>= 1) sum += __shfl_xor(sum, off);
  if ((tid & 63) == 0) red2[tid >> 6] = sum;
  __syncthreads();
  sum = red2[0] + red2[1] + red2[2] + red2[3];
  if (tid == 0) Lsum[q0 + r] = sum;
  f16* prow = P + (size_t)(q0 + r) * ppitch;
#pragma unroll
  for (int e = 0; e < 8; ++e) {
    f16x4 p;
#pragma unroll
    for (int i = 0; i < 4; ++i) p[i] = (f16)v[e][i];
    *(f16x4*)(prow + (size_t)(tid + e * 256) * 4) = p;
  }
}

// ---------------------------------------------------------------------------
// Pass C: Opart^T = XhT * P^T via the k_qkt skeleton (LDS-staged, BK=64).
// Block tile 128 d x 128 q, grid (4, 64, Z); z-slice covers jrange columns.
// A = XhT rows (d), B = P rows (q), both j-contiguous. Writes unscaled fp32
// partial at obase + q*qstride + z*zstride + d*4.
// ---------------------------------------------------------------------------
__global__ __launch_bounds__(256) void k_pv3(
    const f16* __restrict__ XhT, const f16* __restrict__ P,
    char* __restrict__ obase, int ppitch, size_t qstride, size_t zstride,
    int jrange)
{
  __shared__ char sm[2 * 16384];   // A tile [128][64] f16, B tile [128][64] f16
  const int tid  = threadIdx.x;
  const int lane = tid & 63;
  const int w    = tid >> 6;
  const int wm   = (w >> 1) * 64;          // d offset
  const int wn   = (w & 1) * 64;           // q offset
  const int d0   = blockIdx.x * 128;
  const int q0   = blockIdx.y * 128;
  const int z    = blockIdx.z;
  const int jbase = z * jrange;

  // staging: 2 threads per row (r1 = tid>>1, half = tid&1), 4 x 16B each
  const int r1 = tid >> 1;
  const int half = tid & 1;
  int swz[4];
#pragma unroll
  for (int c = 0; c < 4; ++c)
    swz[c] = (r1 * 128 + half * 64 + c * 16) ^ ((r1 & 7) << 4);
  const f16* pA = XhT + (size_t)(d0 + r1) * VPITCH + jbase + half * 32;
  const f16* pB = P   + (size_t)(q0 + r1) * ppitch + jbase + half * 32;

  const int frow = lane & 15;
  const int lhi  = lane >> 4;

  f32x4 acc[4][4] = {};
  const int nsteps = jrange / 64;

  for (int step = 0; step < nsteps; ++step) {
    const int j = step * 64;
    uint4 va[4], vb[4];
#pragma unroll
    for (int c = 0; c < 4; ++c) {
      va[c] = *(const uint4*)(pA + j + c * 8);
      vb[c] = *(const uint4*)(pB + j + c * 8);
    }
    __syncthreads();
#pragma unroll
    for (int c = 0; c < 4; ++c) {
      *(uint4*)(sm +         swz[c]) = va[c];
      *(uint4*)(sm + 16384 + swz[c]) = vb[c];
    }
    __syncthreads();
#pragma unroll
    for (int kk = 0; kk < 2; ++kk) {
      const int kb = kk * 64 + lhi * 16;
      f16x8 af[4], bf[4];
#pragma unroll
      for (int m = 0; m < 4; ++m) {
        int ra = wm + m * 16 + frow;
        int rb = wn + m * 16 + frow;
        af[m] = *(const f16x8*)(sm +         (ra * 128 + (kb ^ ((ra & 7) << 4))));
        bf[m] = *(const f16x8*)(sm + 16384 + (rb * 128 + (kb ^ ((rb & 7) << 4))));
      }
#pragma unroll
      for (int m = 0; m < 4; ++m)
#pragma unroll
        for (int n = 0; n < 4; ++n)
          acc[m][n] = __builtin_amdgcn_mfma_f32_16x16x32_f16(af[m], bf[n], acc[m][n], 0, 0, 0);
    }
  }

  // C row = d = d0 + wm + m*16 + lhi*4 + r ; C col = q = q0 + wn + n*16 + frow
#pragma unroll
  for (int m = 0; m < 4; ++m)
#pragma unroll
    for (int n = 0; n < 4; ++n) {
      const int qg = q0 + wn + n * 16 + frow;
      const int dd = d0 + wm + m * 16 + lhi * 4;
      *(f32x4*)(obase + (size_t)qg * qstride + (size_t)z * zstride
                      + (size_t)dd * 4) = acc[m][n];
    }
}

// ---------------------------------------------------------------------------
// Pass D: Out[q][d] = (sum_z Opart[z][q][d]) / Lsum[q].
// ---------------------------------------------------------------------------
__global__ __launch_bounds__(256) void k_reduce(
    const char* __restrict__ obase, size_t qstride, size_t zstride, int Z,
    const float* __restrict__ Lsum, float* __restrict__ Out)
{
  const int idx = blockIdx.x * 256 + threadIdx.x;
  const int q = idx >> 7;
  const int d4 = idx & 127;
  const char* p = obase + (size_t)q * qstride + (size_t)d4 * 16;
  f32x4 s = *(const f32x4*)p;
  for (int zz = 1; zz < Z; ++zz)
    s += *(const f32x4*)(p + (size_t)zz * zstride);
  float linv = 1.0f / Lsum[q];
  s *= linv;
  *(f32x4*)(Out + (size_t)q * DIM + d4 * 4) = s;
}

// ---------------------------------------------------------------------------
extern "C" void kernel_launch(void* const* d_in, const int* in_sizes, int n_in,
                              void* d_out, int out_size, void* d_ws, size_t ws_size,
                              hipStream_t stream) {
  const float* Wq = (const float*)d_in[0];
  const float* Wk = (const float*)d_in[1];
  const float* X  = (const float*)d_in[2];
  float* Out = (float*)d_out;

  char* w = (char*)d_ws;
  const size_t SPLIT  = (size_t)NSEQ * DIM * 2;          // 8 MB per f16 matrix
  const size_t XBYTES = (size_t)DIM * VPITCH * 2;        // padded XhT
  const size_t WTB    = (size_t)DIM * DIM * 2;           // 512 KB per Wt half
  f16* Qh  = (f16*)(w);
  f16* Ql  = (f16*)(w + SPLIT);
  f16* Kh  = (f16*)(w + 2 * SPLIT);
  f16* Kl  = (f16*)(w + 3 * SPLIT);
  f16* XhT = (f16*)(w + 4 * SPLIT);
  f16* Xh  = (f16*)(w + 4 * SPLIT + XBYTES);
  f16* Xl  = (f16*)(w + 5 * SPLIT + XBYTES);
  f16* Wth = (f16*)(w + 6 * SPLIT + XBYTES);
  f16* Wtl = (f16*)(w + 6 * SPLIT + XBYTES + WTB);
  float* Lsum = (float*)(w + 6 * SPLIT + XBYTES + 2 * WTB);
  const size_t used_base = 6 * SPLIT + XBYTES + 2 * WTB + 32768;
  char* rest = w + used_base;
  const size_t SBYTES_FULL = (size_t)NSEQ * SROWB;       // ~271 MB
  const size_t PBYTES      = (size_t)NSEQ * SPITCH * 2;  // ~135 MB (chunked)
  const size_t OPART1      = (size_t)NSEQ * DIM * 4;     // 16 MB per partial

  float* S; f16* P; int ppitch; int CQ;
  int Z; char* obase; size_t qstride, zstride;
  if (ws_size >= used_base + SBYTES_FULL) {
    // Full S (pitch SPITCH); P f16 overlays first 16 KB of each S row; the
    // dead upper part of each row holds the Z split-j partials (Z x 2 KB).
    S = (float*)rest; P = (f16*)rest; ppitch = 2 * SPITCH; CQ = NSEQ;
    Z = 4;
    obase = rest + 16384;
    qstride = SROWB;
    zstride = 2048;
  } else {
    P = (f16*)rest; ppitch = SPITCH;
    S = (float*)(rest + PBYTES);
    size_t avail = (ws_size > used_base + PBYTES) ? ws_size - used_base - PBYTES : 0;
    CQ = 4096;
    while (CQ > 128 && (size_t)CQ * SROWB > avail) CQ >>= 1;
    size_t schunk = (size_t)CQ * SROWB;
    Z = (int)(schunk / OPART1);
    if (Z > 4) Z = 4;
    if (Z >= 2) {
      obase = (char*)S; qstride = DIM * 4; zstride = OPART1;
    } else {
      Z = 1; obase = (char*)Out; qstride = DIM * 4; zstride = 0;
    }
  }

  const float SCALE = 0.044194173824159216f;  // 1/sqrt(512)
  k_splitx<<<NSEQ * DIM / (256 * 4), 256, 0, stream>>>(X, Xh, Xl);
  k_xt<<<dim3(NSEQ / 64, DIM / 64), 256, 0, stream>>>(X, XhT);
  k_splitwt<<<dim3(8, 8), 256, 0, stream>>>(Wq, Wth, Wtl);
  k_proj<<<dim3(NSEQ / 128, DIM / 128), 256, 0, stream>>>(Xh, Xl, Wth, Wtl, Qh, Ql, SCALE);
  k_splitwt<<<dim3(8, 8), 256, 0, stream>>>(Wk, Wth, Wtl);
  k_proj<<<dim3(NSEQ / 128, DIM / 128), 256, 0, stream>>>(Xh, Xl, Wth, Wtl, Kh, Kl, 1.0f);
  for (int q0 = 0; q0 < NSEQ; q0 += CQ) {
    k_qkt<<<dim3(CQ / 128, NSEQ / 128), 256, 0, stream>>>(Qh, Ql, Kh, Kl, S, q0);
    k_softmax<<<dim3(CQ), 256, 0, stream>>>(S, P, Lsum, q0, ppitch);
  }
  k_pv3<<<dim3(DIM / 128, NSEQ / 128, Z), 256, 0, stream>>>(XhT, P, obase, ppitch,
                                                            qstride, zstride, NSEQ / Z);
  k_reduce<<<NSEQ * (DIM / 4) / 256, 256, 0, stream>>>(obase, qstride, zstride,
                                                       Z, Lsum, Out);
}

// Round 6
// 674.350 us; speedup vs baseline: 1.2020x; 1.2020x over previous
//
#include <hip/hip_runtime.h>
#include <hip/hip_fp16.h>

#define NSEQ 8192
#define DIM  512
#define SPITCH 8256            // f32 elems per S row (NSEQ + 64, kills pow2 stride)
#define SROWB  33024           // bytes per S row
#define VPITCH 8256            // f16 elems per XhT row

typedef _Float16 f16;
typedef _Float16 f16x8 __attribute__((ext_vector_type(8)));
typedef _Float16 f16x4 __attribute__((ext_vector_type(4)));
typedef float    f32x4 __attribute__((ext_vector_type(4)));

// ---------------------------------------------------------------------------
// X (fp32) -> Xh + Xl (f16 hi/lo split), elementwise.
// ---------------------------------------------------------------------------
__global__ __launch_bounds__(256) void k_splitx(const float* __restrict__ X,
                                                f16* __restrict__ Xh,
                                                f16* __restrict__ Xl)
{
  const size_t idx = (size_t)blockIdx.x * 256 + threadIdx.x;
  f32x4 v = *(const f32x4*)(X + idx * 4);
  f16x4 h, l;
#pragma unroll
  for (int i = 0; i < 4; ++i) {
    h[i] = (f16)v[i];
    l[i] = (f16)(v[i] - (float)h[i]);
  }
  *(f16x4*)(Xh + idx * 4) = h;
  *(f16x4*)(Xl + idx * 4) = l;
}

// ---------------------------------------------------------------------------
// W (512x512 fp32) -> Wt^T split: Wth/Wtl[c][k] = split(W[k][c]).
// ---------------------------------------------------------------------------
__global__ __launch_bounds__(256) void k_splitwt(const float* __restrict__ W,
                                                 f16* __restrict__ Th,
                                                 f16* __restrict__ Tl)
{
  __shared__ float T[64][65];
  const int tid = threadIdx.x;
  const int k0 = blockIdx.x * 64;   // input row
  const int c0 = blockIdx.y * 64;   // input col
#pragma unroll
  for (int e = 0; e < 16; ++e) {
    int idx = tid + e * 256;
    T[idx >> 6][idx & 63] = W[(size_t)(k0 + (idx >> 6)) * DIM + c0 + (idx & 63)];
  }
  __syncthreads();
#pragma unroll
  for (int e = 0; e < 16; ++e) {
    int idx = tid + e * 256;
    int cc = idx >> 6, kk = idx & 63;
    float v = T[kk][cc];
    f16 h = (f16)v;
    Th[(size_t)(c0 + cc) * DIM + k0 + kk] = h;
    Tl[(size_t)(c0 + cc) * DIM + k0 + kk] = (f16)(v - (float)h);
  }
}

// ---------------------------------------------------------------------------
// Kernel 0b: XhT[d][j] = f16(X[j][d])  (V in [d][j] layout, padded pitch)
// ---------------------------------------------------------------------------
__global__ __launch_bounds__(256) void k_xt(const float* __restrict__ X,
                                            f16* __restrict__ XhT)
{
  __shared__ float T[64][65];
  const int tid = threadIdx.x;
  const int j0 = blockIdx.x * 64;
  const int d0 = blockIdx.y * 64;
#pragma unroll
  for (int e = 0; e < 16; ++e) {
    int idx = tid + e * 256;
    T[idx >> 6][idx & 63] = X[(size_t)(j0 + (idx >> 6)) * DIM + d0 + (idx & 63)];
  }
  __syncthreads();
#pragma unroll
  for (int e = 0; e < 16; ++e) {
    int idx = tid + e * 256;
    int dd = idx >> 6, jj = idx & 63;
    XhT[(size_t)(d0 + dd) * VPITCH + j0 + jj] = (f16)T[jj][dd];
  }
}

// ---------------------------------------------------------------------------
// Projection via split-f16 MFMA: C = X W  (M=8192, N=512, K=512).
// k_qkt skeleton: 128x128 tile, 4 waves, BK=32, 3-term split.
// Epilogue: c *= scale, split into Oh (f16 hi) + Ol (f16 lo).
// ---------------------------------------------------------------------------
__global__ __launch_bounds__(256) void k_proj(
    const f16* __restrict__ Xh, const f16* __restrict__ Xl,
    const f16* __restrict__ Wth, const f16* __restrict__ Wtl,
    f16* __restrict__ Oh, f16* __restrict__ Ol, float scale)
{
  __shared__ char sm[4 * 8192];   // Xh,Xl,Wth,Wtl tiles: [128][32] f16
  const int tid  = threadIdx.x;
  const int lane = tid & 63;
  const int w    = tid >> 6;
  const int wm   = (w >> 1) * 64;
  const int wn   = (w & 1) * 64;
  const int row0g = blockIdx.x * 128;   // seq rows
  const int col0g = blockIdx.y * 128;   // out channels (Wt rows)

  const int r1 = tid >> 2;
  const int o1 = (tid & 3) * 8;
  const int sw1 = (r1 * 64 + (tid & 3) * 16) ^ ((r1 & 7) << 4);
  const int sw2 = ((r1 + 64) * 64 + (tid & 3) * 16) ^ (((r1 + 64) & 7) << 4);
  const f16* pAh = Xh  + (size_t)(row0g + r1) * DIM + o1;
  const f16* pAl = Xl  + (size_t)(row0g + r1) * DIM + o1;
  const f16* pBh = Wth + (size_t)(col0g + r1) * DIM + o1;
  const f16* pBl = Wtl + (size_t)(col0g + r1) * DIM + o1;
  const int R64 = 64 * DIM;

  const int frow = lane & 15;
  const int fkb  = (lane >> 4) * 16;

  f32x4 acc[4][4] = {};

  for (int step = 0; step < 16; ++step) {
    const int d0 = step * 32;
    uint4 v0 = *(const uint4*)(pAh + d0);
    uint4 v1 = *(const uint4*)(pAh + R64 + d0);
    uint4 v2 = *(const uint4*)(pAl + d0);
    uint4 v3 = *(const uint4*)(pAl + R64 + d0);
    uint4 v4 = *(const uint4*)(pBh + d0);
    uint4 v5 = *(const uint4*)(pBh + R64 + d0);
    uint4 v6 = *(const uint4*)(pBl + d0);
    uint4 v7 = *(const uint4*)(pBl + R64 + d0);
    __syncthreads();
    *(uint4*)(sm +     0 + sw1) = v0;
    *(uint4*)(sm +     0 + sw2) = v1;
    *(uint4*)(sm +  8192 + sw1) = v2;
    *(uint4*)(sm +  8192 + sw2) = v3;
    *(uint4*)(sm + 16384 + sw1) = v4;
    *(uint4*)(sm + 16384 + sw2) = v5;
    *(uint4*)(sm + 24576 + sw1) = v6;
    *(uint4*)(sm + 24576 + sw2) = v7;
    __syncthreads();
    f16x8 aH[4], aL[4], bH[4], bL[4];
#pragma unroll
    for (int m = 0; m < 4; ++m) {
      int ra = wm + m * 16 + frow;
      int rb = wn + m * 16 + frow;
      int sa = (ra * 64 + fkb) ^ ((ra & 7) << 4);
      int sb = (rb * 64 + fkb) ^ ((rb & 7) << 4);
      aH[m] = *(const f16x8*)(sm +     0 + sa);
      aL[m] = *(const f16x8*)(sm +  8192 + sa);
      bH[m] = *(const f16x8*)(sm + 16384 + sb);
      bL[m] = *(const f16x8*)(sm + 24576 + sb);
    }
#pragma unroll
    for (int m = 0; m < 4; ++m)
#pragma unroll
      for (int n = 0; n < 4; ++n) {
        acc[m][n] = __builtin_amdgcn_mfma_f32_16x16x32_f16(aH[m], bH[n], acc[m][n], 0, 0, 0);
        acc[m][n] = __builtin_amdgcn_mfma_f32_16x16x32_f16(aH[m], bL[n], acc[m][n], 0, 0, 0);
        acc[m][n] = __builtin_amdgcn_mfma_f32_16x16x32_f16(aL[m], bH[n], acc[m][n], 0, 0, 0);
      }
  }

  const int row0 = row0g + wm;
  const int col0 = col0g + wn;
#pragma unroll
  for (int m = 0; m < 4; ++m)
#pragma unroll
    for (int n = 0; n < 4; ++n) {
      int row = row0 + m * 16 + (lane >> 4) * 4;
      int col = col0 + n * 16 + frow;
#pragma unroll
      for (int r = 0; r < 4; ++r) {
        float c = acc[m][n][r] * scale;
        f16 h = (f16)c;
        Oh[(size_t)(row + r) * DIM + col] = h;
        Ol[(size_t)(row + r) * DIM + col] = (f16)(c - (float)h);
      }
    }
}

// ---------------------------------------------------------------------------
// Pass A: S = Q K^T via split-f16 MFMA (3 mfma per fragment pair).
// 128x128 block tile, 4 waves (64x64 each), BK=32, XOR-swizzled LDS.
// ---------------------------------------------------------------------------
__global__ __launch_bounds__(256) void k_qkt(
    const f16* __restrict__ Qh, const f16* __restrict__ Ql,
    const f16* __restrict__ Kh, const f16* __restrict__ Kl,
    float* __restrict__ S, int q0)
{
  __shared__ char sm[4 * 8192];
  const int tid  = threadIdx.x;
  const int lane = tid & 63;
  const int w    = tid >> 6;
  const int wm   = (w >> 1) * 64;
  const int wn   = (w & 1) * 64;
  const int qrow0 = q0 + blockIdx.x * 128;
  const int krow0 = blockIdx.y * 128;

  const int r1 = tid >> 2;
  const int o1 = (tid & 3) * 8;
  const int sw1 = (r1 * 64 + (tid & 3) * 16) ^ ((r1 & 7) << 4);
  const int sw2 = ((r1 + 64) * 64 + (tid & 3) * 16) ^ (((r1 + 64) & 7) << 4);
  const f16* pQh = Qh + (size_t)(qrow0 + r1) * DIM + o1;
  const f16* pQl = Ql + (size_t)(qrow0 + r1) * DIM + o1;
  const f16* pKh = Kh + (size_t)(krow0 + r1) * DIM + o1;
  const f16* pKl = Kl + (size_t)(krow0 + r1) * DIM + o1;
  const int R64 = 64 * DIM;

  const int frow = lane & 15;
  const int fkb  = (lane >> 4) * 16;

  f32x4 acc[4][4] = {};

  for (int step = 0; step < 16; ++step) {
    const int d0 = step * 32;
    uint4 v0 = *(const uint4*)(pQh + d0);
    uint4 v1 = *(const uint4*)(pQh + R64 + d0);
    uint4 v2 = *(const uint4*)(pQl + d0);
    uint4 v3 = *(const uint4*)(pQl + R64 + d0);
    uint4 v4 = *(const uint4*)(pKh + d0);
    uint4 v5 = *(const uint4*)(pKh + R64 + d0);
    uint4 v6 = *(const uint4*)(pKl + d0);
    uint4 v7 = *(const uint4*)(pKl + R64 + d0);
    __syncthreads();
    *(uint4*)(sm +     0 + sw1) = v0;
    *(uint4*)(sm +     0 + sw2) = v1;
    *(uint4*)(sm +  8192 + sw1) = v2;
    *(uint4*)(sm +  8192 + sw2) = v3;
    *(uint4*)(sm + 16384 + sw1) = v4;
    *(uint4*)(sm + 16384 + sw2) = v5;
    *(uint4*)(sm + 24576 + sw1) = v6;
    *(uint4*)(sm + 24576 + sw2) = v7;
    __syncthreads();
    f16x8 aH[4], aL[4], bH[4], bL[4];
#pragma unroll
    for (int m = 0; m < 4; ++m) {
      int ra = wm + m * 16 + frow;
      int rb = wn + m * 16 + frow;
      int sa = (ra * 64 + fkb) ^ ((ra & 7) << 4);
      int sb = (rb * 64 + fkb) ^ ((rb & 7) << 4);
      aH[m] = *(const f16x8*)(sm +     0 + sa);
      aL[m] = *(const f16x8*)(sm +  8192 + sa);
      bH[m] = *(const f16x8*)(sm + 16384 + sb);
      bL[m] = *(const f16x8*)(sm + 24576 + sb);
    }
#pragma unroll
    for (int m = 0; m < 4; ++m)
#pragma unroll
      for (int n = 0; n < 4; ++n) {
        acc[m][n] = __builtin_amdgcn_mfma_f32_16x16x32_f16(aH[m], bH[n], acc[m][n], 0, 0, 0);
        acc[m][n] = __builtin_amdgcn_mfma_f32_16x16x32_f16(aH[m], bL[n], acc[m][n], 0, 0, 0);
        acc[m][n] = __builtin_amdgcn_mfma_f32_16x16x32_f16(aL[m], bH[n], acc[m][n], 0, 0, 0);
      }
  }

  const int srow0 = blockIdx.x * 128 + wm;
  const int scol0 = krow0 + wn;
#pragma unroll
  for (int m = 0; m < 4; ++m)
#pragma unroll
    for (int n = 0; n < 4; ++n) {
      int row = srow0 + m * 16 + (lane >> 4) * 4;
      int col = scol0 + n * 16 + (lane & 15);
#pragma unroll
      for (int r = 0; r < 4; ++r)
        S[(size_t)(row + r) * SPITCH + col] = acc[m][n][r];
    }
}

// ---------------------------------------------------------------------------
// Pass B: one block per row. Row max + sum(exp), writes P=f16(exp(s-m)) and
// the row sum.
// ---------------------------------------------------------------------------
__global__ __launch_bounds__(256) void k_softmax(
    const float* __restrict__ S, f16* __restrict__ P,
    float* __restrict__ Lsum, int q0, int ppitch)
{
  __shared__ float red[4], red2[4];
  const int tid = threadIdx.x;
  const int r = blockIdx.x;
  const float* srow = S + (size_t)r * SPITCH;
  f32x4 v[8];
#pragma unroll
  for (int e = 0; e < 8; ++e)
    v[e] = *(const f32x4*)(srow + (size_t)(tid + e * 256) * 4);
  float m = -3.0e38f;
#pragma unroll
  for (int e = 0; e < 8; ++e)
#pragma unroll
    for (int i = 0; i < 4; ++i) m = fmaxf(m, v[e][i]);
#pragma unroll
  for (int off = 32; off; off >>= 1) m = fmaxf(m, __shfl_xor(m, off));
  if ((tid & 63) == 0) red[tid >> 6] = m;
  __syncthreads();
  m = fmaxf(fmaxf(red[0], red[1]), fmaxf(red[2], red[3]));
  float sum = 0.f;
#pragma unroll
  for (int e = 0; e < 8; ++e)
#pragma unroll
    for (int i = 0; i < 4; ++i) {
      float p = __expf(v[e][i] - m);
      v[e][i] = p;
      sum += p;
    }
#pragma unroll
  for (int off = 32; off; off >>= 1) sum += __shfl_xor(sum, off);
  if ((tid & 63) == 0) red2[tid >> 6] = sum;
  __syncthreads();
  sum = red2[0] + red2[1] + red2[2] + red2[3];
  if (tid == 0) Lsum[q0 + r] = sum;
  f16* prow = P + (size_t)(q0 + r) * ppitch;
#pragma unroll
  for (int e = 0; e < 8; ++e) {
    f16x4 p;
#pragma unroll
    for (int i = 0; i < 4; ++i) p[i] = (f16)v[e][i];
    *(f16x4*)(prow + (size_t)(tid + e * 256) * 4) = p;
  }
}

// ---------------------------------------------------------------------------
// Pass C: Opart^T = XhT * P^T, L2-direct, no LDS, no barriers.
// Block = 4 waves = 32 q x 512 d. 1-D grid of 256*Z blocks, decoded so
// xcd (= bid & 7, the round-robin XCD heuristic) determines the z-slice:
// each XCD then works on ONE 2 MB XhT slice -> L2-resident A, P streamed.
// Writes unscaled fp32 partial at obase + q*qstride + z*zstride + d*4.
// ---------------------------------------------------------------------------
__global__ __launch_bounds__(256, 4) void k_pv2(
    const f16* __restrict__ XhT, const f16* __restrict__ P,
    char* __restrict__ obase, int ppitch, size_t qstride, size_t zstride,
    int jrange, int Z)
{
  const int tid  = threadIdx.x;
  const int lane = tid & 63;
  const int w    = tid >> 6;
  const int frow = lane & 15;
  const int lhi  = lane >> 4;

  const int bid = blockIdx.x;
  const int xcd = bid & 7;
  const int g   = bid >> 3;
  const int pz  = 8 / Z;                       // XCDs per z-slice (Z in {1,2,4})
  const int z   = xcd / pz;
  const int q0  = (g * pz + (xcd % pz)) * 32;  // bijective over (z, qblk)
  const int jbase = z * jrange;

  const f16* pa  = XhT + (size_t)(w * 128 + frow) * VPITCH + jbase + lhi * 8;
  const f16* pb0 = P + (size_t)(q0 + frow) * ppitch + jbase + lhi * 8;
  const f16* pb1 = pb0 + (size_t)16 * ppitch;

  f32x4 acc[8][2] = {};
  const int nsteps = jrange / 32;
  for (int s = 0; s < nsteps; ++s) {
    const int j = s * 32;
    f16x8 b0 = *(const f16x8*)(pb0 + j);
    f16x8 b1 = *(const f16x8*)(pb1 + j);
#pragma unroll
    for (int m2 = 0; m2 < 8; ++m2) {
      f16x8 a = *(const f16x8*)(pa + (size_t)(m2 * 16) * VPITCH + j);
      acc[m2][0] = __builtin_amdgcn_mfma_f32_16x16x32_f16(a, b0, acc[m2][0], 0, 0, 0);
      acc[m2][1] = __builtin_amdgcn_mfma_f32_16x16x32_f16(a, b1, acc[m2][1], 0, 0, 0);
    }
  }

  // C row = d = w*128 + m2*16 + lhi*4 + r ; C col = q = q0 + n2*16 + frow
#pragma unroll
  for (int m2 = 0; m2 < 8; ++m2)
#pragma unroll
    for (int n2 = 0; n2 < 2; ++n2) {
      const int qg = q0 + n2 * 16 + frow;
      char* p = obase + (size_t)qg * qstride + (size_t)z * zstride
                      + (size_t)(w * 128 + m2 * 16 + lhi * 4) * 4;
      *(f32x4*)p = acc[m2][n2];
    }
}

// ---------------------------------------------------------------------------
// Pass D: Out[q][d] = (sum_z Opart[z][q][d]) / Lsum[q].
// ---------------------------------------------------------------------------
__global__ __launch_bounds__(256) void k_reduce(
    const char* __restrict__ obase, size_t qstride, size_t zstride, int Z,
    const float* __restrict__ Lsum, float* __restrict__ Out)
{
  const int idx = blockIdx.x * 256 + threadIdx.x;
  const int q = idx >> 7;
  const int d4 = idx & 127;
  const char* p = obase + (size_t)q * qstride + (size_t)d4 * 16;
  f32x4 s = *(const f32x4*)p;
  for (int zz = 1; zz < Z; ++zz)
    s += *(const f32x4*)(p + (size_t)zz * zstride);
  float linv = 1.0f / Lsum[q];
  s *= linv;
  *(f32x4*)(Out + (size_t)q * DIM + d4 * 4) = s;
}

// ---------------------------------------------------------------------------
extern "C" void kernel_launch(void* const* d_in, const int* in_sizes, int n_in,
                              void* d_out, int out_size, void* d_ws, size_t ws_size,
                              hipStream_t stream) {
  const float* Wq = (const float*)d_in[0];
  const float* Wk = (const float*)d_in[1];
  const float* X  = (const float*)d_in[2];
  float* Out = (float*)d_out;

  char* w = (char*)d_ws;
  const size_t SPLIT  = (size_t)NSEQ * DIM * 2;          // 8 MB per f16 matrix
  const size_t XBYTES = (size_t)DIM * VPITCH * 2;        // padded XhT
  const size_t WTB    = (size_t)DIM * DIM * 2;           // 512 KB per Wt half
  f16* Qh  = (f16*)(w);
  f16* Ql  = (f16*)(w + SPLIT);
  f16* Kh  = (f16*)(w + 2 * SPLIT);
  f16* Kl  = (f16*)(w + 3 * SPLIT);
  f16* XhT = (f16*)(w + 4 * SPLIT);
  f16* Xh  = (f16*)(w + 4 * SPLIT + XBYTES);
  f16* Xl  = (f16*)(w + 5 * SPLIT + XBYTES);
  f16* Wth = (f16*)(w + 6 * SPLIT + XBYTES);
  f16* Wtl = (f16*)(w + 6 * SPLIT + XBYTES + WTB);
  float* Lsum = (float*)(w + 6 * SPLIT + XBYTES + 2 * WTB);
  const size_t used_base = 6 * SPLIT + XBYTES + 2 * WTB + 32768;
  char* rest = w + used_base;
  const size_t SBYTES_FULL = (size_t)NSEQ * SROWB;       // ~271 MB
  const size_t PBYTES      = (size_t)NSEQ * SPITCH * 2;  // ~135 MB (chunked)
  const size_t OPART1      = (size_t)NSEQ * DIM * 4;     // 16 MB per partial

  float* S; f16* P; int ppitch; int CQ;
  int Z; char* obase; size_t qstride, zstride;
  if (ws_size >= used_base + SBYTES_FULL) {
    // Full S (pitch SPITCH); P f16 overlays first 16 KB of each S row; the
    // dead upper part of each row holds the Z split-j partials (Z x 2 KB).
    S = (float*)rest; P = (f16*)rest; ppitch = 2 * SPITCH; CQ = NSEQ;
    Z = 4;
    obase = rest + 16384;
    qstride = SROWB;
    zstride = 2048;
  } else {
    P = (f16*)rest; ppitch = SPITCH;
    S = (float*)(rest + PBYTES);
    size_t avail = (ws_size > used_base + PBYTES) ? ws_size - used_base - PBYTES : 0;
    CQ = 4096;
    while (CQ > 128 && (size_t)CQ * SROWB > avail) CQ >>= 1;
    size_t schunk = (size_t)CQ * SROWB;
    int zc = (int)(schunk / OPART1);
    Z = (zc >= 4) ? 4 : (zc >= 2) ? 2 : 1;   // power of 2 for XCD decode
    if (Z >= 2) {
      obase = (char*)S; qstride = DIM * 4; zstride = OPART1;
    } else {
      Z = 1; obase = (char*)Out; qstride = DIM * 4; zstride = 0;
    }
  }

  const float SCALE = 0.044194173824159216f;  // 1/sqrt(512)
  k_splitx<<<NSEQ * DIM / (256 * 4), 256, 0, stream>>>(X, Xh, Xl);
  k_xt<<<dim3(NSEQ / 64, DIM / 64), 256, 0, stream>>>(X, XhT);
  k_splitwt<<<dim3(8, 8), 256, 0, stream>>>(Wq, Wth, Wtl);
  k_proj<<<dim3(NSEQ / 128, DIM / 128), 256, 0, stream>>>(Xh, Xl, Wth, Wtl, Qh, Ql, SCALE);
  k_splitwt<<<dim3(8, 8), 256, 0, stream>>>(Wk, Wth, Wtl);
  k_proj<<<dim3(NSEQ / 128, DIM / 128), 256, 0, stream>>>(Xh, Xl, Wth, Wtl, Kh, Kl, 1.0f);
  for (int q0 = 0; q0 < NSEQ; q0 += CQ) {
    k_qkt<<<dim3(CQ / 128, NSEQ / 128), 256, 0, stream>>>(Qh, Ql, Kh, Kl, S, q0);
    k_softmax<<<dim3(CQ), 256, 0, stream>>>(S, P, Lsum, q0, ppitch);
  }
  k_pv2<<<dim3(256 * Z), 256, 0, stream>>>(XhT, P, obase, ppitch,
                                           qstride, zstride, NSEQ / Z, Z);
  k_reduce<<<NSEQ * (DIM / 4) / 256, 256, 0, stream>>>(obase, qstride, zstride,
                                                       Z, Lsum, Out);
}